// Round 7
// baseline (282.952 us; speedup 1.0000x reference)
//
#include <hip/hip_runtime.h>
#include <hip/hip_bf16.h>
#include <cstdint>
#include <cstddef>

typedef __hip_bfloat16 bf16;
typedef __attribute__((ext_vector_type(8))) __bf16 bf16x8;
typedef __attribute__((ext_vector_type(4))) float floatx4;

#define GPTR(p) ((const __attribute__((address_space(1))) void*)(p))
#define LPTR(p) ((__attribute__((address_space(3))) void*)(p))

__device__ __forceinline__ floatx4 mfma16(bf16x8 a, bf16x8 b, floatx4 c) {
  return __builtin_amdgcn_mfma_f32_16x16x32_bf16(a, b, c, 0, 0, 0);
}

// ---------------------------------------------------------------------------
// fp32 -> bf16 bulk convert
// ---------------------------------------------------------------------------
__global__ __launch_bounds__(256) void cvt_bf16(const float* __restrict__ in,
                                                bf16* __restrict__ out, int n4) {
  for (int i = blockIdx.x * 256 + threadIdx.x; i < n4; i += gridDim.x * 256) {
    float4 v = ((const float4*)in)[i];
    alignas(8) bf16 t[4] = {__float2bfloat16(v.x), __float2bfloat16(v.y),
                            __float2bfloat16(v.z), __float2bfloat16(v.w)};
    *(uint64_t*)(out + (size_t)i * 4) = *(const uint64_t*)t;
  }
}

// Fused Wq/Wk/Wv convert: one launch instead of three (saves dispatch
// overhead; sizes 262144 + 65536 + 65536 float4 = 393216 = 1536 blocks).
__global__ __launch_bounds__(256) void cvt_w3(const float* __restrict__ wq,
                                              const float* __restrict__ wk,
                                              const float* __restrict__ wv,
                                              bf16* __restrict__ oq,
                                              bf16* __restrict__ ok,
                                              bf16* __restrict__ ov) {
  int i = blockIdx.x * 256 + threadIdx.x;
  const float* in;
  bf16* out;
  int j;
  if (i < 262144) {
    in = wq; out = oq; j = i;
  } else if (i < 327680) {
    in = wk; out = ok; j = i - 262144;
  } else {
    in = wv; out = ov; j = i - 327680;
  }
  float4 v = ((const float4*)in)[j];
  alignas(8) bf16 t[4] = {__float2bfloat16(v.x), __float2bfloat16(v.y),
                          __float2bfloat16(v.z), __float2bfloat16(v.w)};
  *(uint64_t*)(out + (size_t)j * 4) = *(const uint64_t*)t;
}

// ---------------------------------------------------------------------------
// Fused QKV projection: A[8192,1024](bf16) @ [Wq;Wk;Wv](bf16)^T.
// m97 structure: 128x128 tile, BK=32, both sides global_load_lds width=16.
// q is scaled by 0.125 * log2(e): downstream softmax runs in exp2 domain
// (S and the q.E bias table inherit the factor automatically).
// ---------------------------------------------------------------------------
__global__ __launch_bounds__(256) void gemm_qkv(
    const bf16* __restrict__ A, const bf16* __restrict__ Wq,
    const bf16* __restrict__ Wk, const bf16* __restrict__ Wv,
    bf16* __restrict__ qout, bf16* __restrict__ kout,
    bf16* __restrict__ vTout) {
  __shared__ alignas(16) bf16 As[128 * 32];
  __shared__ alignas(16) bf16 Bs[128 * 32];
  const int tid = threadIdx.x;
  const int lane = tid & 63;
  const int w = tid >> 6;
  const int wr = w >> 1, wc = w & 1;
  const int quad = lane >> 4, c = lane & 15;
  const int m0 = blockIdx.y * 128;
  const int nb = blockIdx.x;

  int mode, nloc;
  const bf16* Wp;
  if (nb < 8) {
    mode = 1; Wp = Wq + (size_t)nb * 128 * 1024; nloc = nb * 128;
  } else if (nb < 10) {
    mode = 2; Wp = Wk + (size_t)(nb - 8) * 128 * 1024; nloc = (nb - 8) * 128;
  } else {
    mode = 3; Wp = Wv + (size_t)(nb - 10) * 128 * 1024; nloc = (nb - 10) * 128;
  }

  const int i0 = tid, i1 = tid + 256;
  const bf16* ga0 = A + (size_t)(m0 + (i0 >> 2)) * 1024 + (i0 & 3) * 8;
  const bf16* ga1 = A + (size_t)(m0 + (i1 >> 2)) * 1024 + (i1 & 3) * 8;
  const bf16* gb0 = Wp + (size_t)(i0 >> 2) * 1024 + (i0 & 3) * 8;
  const bf16* gb1 = Wp + (size_t)(i1 >> 2) * 1024 + (i1 & 3) * 8;

  floatx4 acc[4][4] = {};

  for (int kt = 0; kt < 32; ++kt) {
    if (kt) __syncthreads();
    __builtin_amdgcn_global_load_lds(GPTR(ga0), LPTR(&As[i0 * 8]), 16, 0, 0);
    __builtin_amdgcn_global_load_lds(GPTR(ga1), LPTR(&As[i1 * 8]), 16, 0, 0);
    __builtin_amdgcn_global_load_lds(GPTR(gb0), LPTR(&Bs[i0 * 8]), 16, 0, 0);
    __builtin_amdgcn_global_load_lds(GPTR(gb1), LPTR(&Bs[i1 * 8]), 16, 0, 0);
    ga0 += 32; ga1 += 32; gb0 += 32; gb1 += 32;
    __syncthreads();
    bf16x8 af[4], bfr[4];
#pragma unroll
    for (int i = 0; i < 4; ++i)
      af[i] = *(const bf16x8*)&As[(wr * 64 + i * 16 + c) * 32 + quad * 8];
#pragma unroll
    for (int j = 0; j < 4; ++j)
      bfr[j] = *(const bf16x8*)&Bs[(wc * 64 + j * 16 + c) * 32 + quad * 8];
#pragma unroll
    for (int i = 0; i < 4; ++i)
#pragma unroll
      for (int j = 0; j < 4; ++j)
        acc[i][j] = mfma16(af[i], bfr[j], acc[i][j]);
  }

  if (mode == 3) {  // vT[((b*4+g)*64+d)*1024+t]: 4 consecutive t -> 8B store
#pragma unroll
    for (int i = 0; i < 4; ++i)
#pragma unroll
      for (int j = 0; j < 4; ++j) {
        int m = m0 + wr * 64 + i * 16 + quad * 4;
        int n = nloc + wc * 64 + j * 16 + c;
        int b = m >> 10, t = m & 1023, g = n >> 6, d = n & 63;
        alignas(8) bf16 tmp[4];
#pragma unroll
        for (int r = 0; r < 4; ++r) tmp[r] = __float2bfloat16(acc[i][j][r]);
        *(uint64_t*)(vTout + (((size_t)(b * 4 + g)) * 64 + d) * 1024 + t) =
            *(const uint64_t*)tmp;
      }
    return;
  }

  // 0.125 (1/sqrt(hd)) * 1.44269504 (log2 e): softmax in exp2 domain.
  const float scale = (mode == 1) ? 0.18033688f : 1.0f;
#pragma unroll
  for (int i = 0; i < 4; ++i)
#pragma unroll
    for (int j = 0; j < 4; ++j)
#pragma unroll
      for (int r = 0; r < 4; ++r) {
        int m = m0 + wr * 64 + i * 16 + quad * 4 + r;
        int n = nloc + wc * 64 + j * 16 + c;
        int b = m >> 10, t = m & 1023;
        bf16 v = __float2bfloat16(acc[i][j][r] * scale);
        if (mode == 1) {
          int h = n >> 6;
          qout[(((size_t)(b * 16 + h)) * 1024 + t) * 64 + (n & 63)] = v;
        } else {
          int g = n >> 6;
          kout[(((size_t)(b * 4 + g)) * 1024 + t) * 64 + (n & 63)] = v;
        }
      }
}

// ---------------------------------------------------------------------------
// O-projection: attn[8192,1024](bf16) @ Wo(bf16)^T -> fp32 d_out.
// ---------------------------------------------------------------------------
__global__ __launch_bounds__(256) void gemm_o(const bf16* __restrict__ A,
                                              const bf16* __restrict__ W,
                                              float* __restrict__ out) {
  __shared__ alignas(16) bf16 As[128 * 32];
  __shared__ alignas(16) bf16 Bs[128 * 32];
  const int tid = threadIdx.x;
  const int lane = tid & 63;
  const int w = tid >> 6;
  const int wr = w >> 1, wc = w & 1;
  const int quad = lane >> 4, c = lane & 15;
  const int m0 = blockIdx.y * 128, n0 = blockIdx.x * 128;

  const int i0 = tid, i1 = tid + 256;
  const bf16* ga0 = A + (size_t)(m0 + (i0 >> 2)) * 1024 + (i0 & 3) * 8;
  const bf16* ga1 = A + (size_t)(m0 + (i1 >> 2)) * 1024 + (i1 & 3) * 8;
  const bf16* gb0 = W + (size_t)(n0 + (i0 >> 2)) * 1024 + (i0 & 3) * 8;
  const bf16* gb1 = W + (size_t)(n0 + (i1 >> 2)) * 1024 + (i1 & 3) * 8;

  floatx4 acc[4][4] = {};

  for (int kt = 0; kt < 32; ++kt) {
    if (kt) __syncthreads();
    __builtin_amdgcn_global_load_lds(GPTR(ga0), LPTR(&As[i0 * 8]), 16, 0, 0);
    __builtin_amdgcn_global_load_lds(GPTR(ga1), LPTR(&As[i1 * 8]), 16, 0, 0);
    __builtin_amdgcn_global_load_lds(GPTR(gb0), LPTR(&Bs[i0 * 8]), 16, 0, 0);
    __builtin_amdgcn_global_load_lds(GPTR(gb1), LPTR(&Bs[i1 * 8]), 16, 0, 0);
    ga0 += 32; ga1 += 32; gb0 += 32; gb1 += 32;
    __syncthreads();
    bf16x8 af[4], bfr[4];
#pragma unroll
    for (int i = 0; i < 4; ++i)
      af[i] = *(const bf16x8*)&As[(wr * 64 + i * 16 + c) * 32 + quad * 8];
#pragma unroll
    for (int j = 0; j < 4; ++j)
      bfr[j] = *(const bf16x8*)&Bs[(wc * 64 + j * 16 + c) * 32 + quad * 8];
#pragma unroll
    for (int i = 0; i < 4; ++i)
#pragma unroll
      for (int j = 0; j < 4; ++j)
        acc[i][j] = mfma16(af[i], bfr[j], acc[i][j]);
  }

#pragma unroll
  for (int i = 0; i < 4; ++i)
#pragma unroll
    for (int j = 0; j < 4; ++j)
#pragma unroll
      for (int r = 0; r < 4; ++r) {
        int m = m0 + wr * 64 + i * 16 + quad * 4 + r;
        int n = n0 + wc * 64 + j * 16 + c;
        out[(size_t)m * 1024 + n] = acc[i][j][r];
      }
}

// ---------------------------------------------------------------------------
// Staged 64x64 bf16 tile with XOR-8 column-block swizzle (verified r0).
// ---------------------------------------------------------------------------
__device__ __forceinline__ void stage_tile_swz(const bf16* __restrict__ g,
                                               int gstride, bf16* __restrict__ dst,
                                               int tid) {
#pragma unroll
  for (int s = 0; s < 2; ++s) {
    int f = s * 256 + tid;
    int r = f >> 3, cb = f & 7;
    int cbg = cb ^ (r & 7);
    __builtin_amdgcn_global_load_lds(GPTR(g + (size_t)r * gstride + cbg * 8),
                                     LPTR(dst + f * 8), 16, 0, 0);
  }
}

__device__ __forceinline__ bf16x8 read_frag_swz(const bf16* __restrict__ tile,
                                                int row, int cb) {
  return *(const bf16x8*)&tile[row * 64 + ((cb ^ (row & 7)) * 8)];
}

// ---------------------------------------------------------------------------
// Flash attention, S^T = K.Q^T form.  Round-7 = r6 (127.6us winner) +
//   1. XCD-chunked block swizzle (T1, bijective; 2048 blocks % 8 == 0):
//      physical id p round-robins XCDs; logical = (p&7)*256 + p>>3 puts
//      all 16 q-blocks of each bh (and all heads of each b) on ONE XCD ->
//      K/V panel (1MB per b) stays in that XCD's 4MB L2 -> stage drains at
//      barrier A become L2-latency instead of HBM.  Pre-committed check:
//      FETCH_SIZE 41.3 MB -> ~25 MB; if unchanged, the p%8 dispatch
//      assumption is wrong.
//   2. exp2-domain softmax: q carries 0.125*log2e from gemm_qkv; exp ->
//      native v_exp_f32 (2^x), defer threshold 8 nats -> 11.5 bits.
// LDS: qEl 33792 + K/P 9216 + V 8192 = 51200 -> 3 blocks/CU.
// ---------------------------------------------------------------------------
__global__ __launch_bounds__(256, 3) void attn_kernel(
    const bf16* __restrict__ q_ws, const bf16* __restrict__ k_ws,
    const bf16* __restrict__ vT, const float* __restrict__ E,
    bf16* __restrict__ out) {
  __shared__ alignas(16) bf16 qEl[64 * 264];  // bias table, rows lane-private
  __shared__ alignas(16) bf16 Ks[64 * 72];    // K tile (staged 64x64) / P rows
  __shared__ alignas(16) bf16 Vs[64 * 64];    // V^T tile
  const int tid = threadIdx.x;
  const int lane = tid & 63, w = tid >> 6;
  const int quad = lane >> 4, c = lane & 15;
  // XCD-chunked swizzle (see header comment)
  const int phys = blockIdx.y * 16 + blockIdx.x;
  const int logical = (phys & 7) * 256 + (phys >> 3);
  const int bh = logical >> 4;
  const int b = bh >> 4, h = bh & 15, g = h >> 2;
  const int qb = (logical & 15) * 64 + w * 16;

  const bf16* qrow = q_ws + ((size_t)bh * 1024 + qb + c) * 64;
  bf16x8 qf0 = *(const bf16x8*)(qrow + quad * 8);
  bf16x8 qf1 = *(const bf16x8*)(qrow + 32 + quad * 8);

  // qE[qlocal][p] = q.E[p]  (wave's rows w*16..w*16+15; p in [0,254])
  for (int jn = 0; jn < 16; ++jn) {
    int er = jn * 16 + c;
    er = er > 254 ? 254 : er;
    const float* Ep = E + (size_t)er * 64;
    float4 e0 = *(const float4*)(Ep + quad * 8);
    float4 e1 = *(const float4*)(Ep + quad * 8 + 4);
    float4 e2 = *(const float4*)(Ep + 32 + quad * 8);
    float4 e3 = *(const float4*)(Ep + 32 + quad * 8 + 4);
    alignas(16) bf16 t0b[8] = {
        __float2bfloat16(e0.x), __float2bfloat16(e0.y), __float2bfloat16(e0.z),
        __float2bfloat16(e0.w), __float2bfloat16(e1.x), __float2bfloat16(e1.y),
        __float2bfloat16(e1.z), __float2bfloat16(e1.w)};
    alignas(16) bf16 t1b[8] = {
        __float2bfloat16(e2.x), __float2bfloat16(e2.y), __float2bfloat16(e2.z),
        __float2bfloat16(e2.w), __float2bfloat16(e3.x), __float2bfloat16(e3.y),
        __float2bfloat16(e3.z), __float2bfloat16(e3.w)};
    floatx4 a = {};
    a = mfma16(qf0, *(const bf16x8*)t0b, a);
    a = mfma16(qf1, *(const bf16x8*)t1b, a);
#pragma unroll
    for (int r = 0; r < 4; ++r)
      qEl[(w * 16 + quad * 4 + r) * 264 + jn * 16 + c] = __float2bfloat16(a[r]);
  }
  __syncthreads();  // qEl ready for all waves

  const bf16* rowE = qEl + (size_t)(w * 16 + c) * 264;
  bf16* rowP = Ks + (size_t)(w * 16 + c) * 72;
  float mrow = -1e30f, lpart = 0.f;
  floatx4 o[4] = {};
  const bf16* kbase = k_ws + (size_t)(b * 4 + g) * 1024 * 64;
  const bf16* vbase = vT + (size_t)(b * 4 + g) * 64 * 1024;
  const float blo = __bfloat162float(rowE[254]);
  const float bhi = __bfloat162float(rowE[0]);

  for (int t0 = 0; t0 < 1024; t0 += 64) {
    stage_tile_swz(kbase + (size_t)t0 * 64, 64, Ks, tid);
    stage_tile_swz(vbase + t0, 1024, Vs, tid);
    __syncthreads();  // A: staging landed
    floatx4 S[4];
#pragma unroll
    for (int j = 0; j < 4; ++j) {
      bf16x8 kf0 = read_frag_swz(Ks, j * 16 + c, quad);
      bf16x8 kf1 = read_frag_swz(Ks, j * 16 + c, quad + 4);
      floatx4 z = {};
      z = mfma16(kf0, qf0, z);
      S[j] = mfma16(kf1, qf1, z);
    }
    const int dlt0 = qb + c - t0;
    if (t0 <= qb - 190) {
#pragma unroll
      for (int j = 0; j < 4; ++j)
#pragma unroll
        for (int r = 0; r < 4; ++r) S[j][r] += blo;
    } else if (t0 >= qb + 142) {
#pragma unroll
      for (int j = 0; j < 4; ++j)
#pragma unroll
        for (int r = 0; r < 4; ++r) S[j][r] += bhi;
    } else {
#pragma unroll
      for (int j = 0; j < 4; ++j)
#pragma unroll
        for (int r = 0; r < 4; ++r) {
          int dlt = dlt0 - j * 16 - quad * 4 - r;
          dlt = dlt > 127 ? 127 : (dlt < -127 ? -127 : dlt);
          S[j][r] += __bfloat162float(rowE[dlt + 127]);
        }
    }
    // --- T13 defer-rescale online softmax (exp2 domain)
    float mx = S[0][0];
#pragma unroll
    for (int j = 0; j < 4; ++j)
#pragma unroll
      for (int r = 0; r < 4; ++r) mx = fmaxf(mx, S[j][r]);
    if (__ballot(mx > mrow + 11.5f)) {
      // rare path (tile 0 + genuine max growth): full reduce + rescale
      float fm = fmaxf(mx, __shfl_xor(mx, 16, 64));
      fm = fmaxf(fm, __shfl_xor(fm, 32, 64));
      float nm = fmaxf(mrow, fm);
      float alpha = exp2f(mrow - nm);
      float av[4];
#pragma unroll
      for (int r = 0; r < 4; ++r) av[r] = __shfl(alpha, quad * 4 + r, 64);
#pragma unroll
      for (int jj = 0; jj < 4; ++jj)
#pragma unroll
        for (int r = 0; r < 4; ++r) o[jj][r] *= av[r];
      lpart *= alpha;
      mrow = nm;
    }
    float rs = 0.f;
#pragma unroll
    for (int j = 0; j < 4; ++j)
#pragma unroll
      for (int r = 0; r < 4; ++r) {
        float p = exp2f(S[j][r] - mrow);  // bounded by 2^11.5
        S[j][r] = p;
        rs += p;
      }
    lpart += rs;  // per-lane partial (this quad's kv slice); reduced at end
    __syncthreads();  // B: K frags consumed; Ks reusable as P
#pragma unroll
    for (int j = 0; j < 4; ++j) {
      alignas(8) bf16 tmp[4];
#pragma unroll
      for (int r = 0; r < 4; ++r) tmp[r] = __float2bfloat16(S[j][r]);
      *(uint64_t*)(rowP + j * 16 + quad * 4) = *(const uint64_t*)tmp;
    }
    __threadfence_block();
    __builtin_amdgcn_wave_barrier();
    bf16x8 pf0 = *(const bf16x8*)(rowP + quad * 8);
    bf16x8 pf1 = *(const bf16x8*)(rowP + 32 + quad * 8);
#pragma unroll
    for (int jj = 0; jj < 4; ++jj) {
      bf16x8 vf0 = read_frag_swz(Vs, jj * 16 + c, quad);
      bf16x8 vf1 = read_frag_swz(Vs, jj * 16 + c, quad + 4);
      o[jj] = mfma16(pf0, vf0, o[jj]);
      o[jj] = mfma16(pf1, vf1, o[jj]);
    }
    __syncthreads();  // C: P/V consumed; safe to restage
  }

  // one-time l reduction: per-lane quad partials -> row totals
  float lsum = lpart + __shfl_xor(lpart, 16, 64);
  lsum += __shfl_xor(lsum, 32, 64);
  float lr4[4];
#pragma unroll
  for (int r = 0; r < 4; ++r) lr4[r] = __shfl(lsum, quad * 4 + r, 64);
#pragma unroll
  for (int jj = 0; jj < 4; ++jj)
#pragma unroll
    for (int r = 0; r < 4; ++r) {
      int qi = qb + quad * 4 + r;
      out[(((size_t)b * 1024 + qi) * 16 + h) * 64 + jj * 16 + c] =
          __float2bfloat16(o[jj][r] / lr4[r]);
    }
}

// ---------------------------------------------------------------------------
// Memory plan (unchanged, proven):
//   d_out (32 MB fp32): [0,16M) q bf16 | [16M,32M) x_bf16.
//   ws: k 4MB @0 | vT 4MB @4M | attn 16MB @8M
//   Wq/Wk/Wv_bf @8M/10M/10.5M (attn region, dead before attn_kernel writes).
//   Wo_bf @0 (k region; converted AFTER attn_kernel consumed k).
// ---------------------------------------------------------------------------
extern "C" void kernel_launch(void* const* d_in, const int* in_sizes, int n_in,
                              void* d_out, int out_size, void* d_ws,
                              size_t ws_size, hipStream_t stream) {
  const float* x = (const float*)d_in[0];
  const float* Wq = (const float*)d_in[1];
  const float* Wk = (const float*)d_in[2];
  const float* Wv = (const float*)d_in[3];
  const float* Wo = (const float*)d_in[4];
  const float* E = (const float*)d_in[5];

  char* ws = (char*)d_ws;
  bf16* q_ws = (bf16*)d_out;                           // [0,16M) of d_out
  bf16* x_bf = (bf16*)((char*)d_out + (16ull << 20));  // [16M,32M) of d_out
  bf16* k_ws = (bf16*)(ws);
  bf16* vT = (bf16*)(ws + (4ull << 20));
  bf16* attn = (bf16*)(ws + (8ull << 20));
  bf16* Wq_bf = (bf16*)(ws + (8ull << 20));            // 2 MB   (attn region)
  bf16* Wk_bf = (bf16*)(ws + (10ull << 20));           // 0.5 MB (attn region)
  bf16* Wv_bf = (bf16*)(ws + (10ull << 20) + (512ull << 10));  // 0.5 MB
  bf16* Wo_bf = (bf16*)(ws);                           // 2 MB   (k region)
  float* outp = (float*)d_out;

  cvt_bf16<<<2048, 256, 0, stream>>>(x, x_bf, 2097152);
  cvt_w3<<<1536, 256, 0, stream>>>(Wq, Wk, Wv, Wq_bf, Wk_bf, Wv_bf);
  gemm_qkv<<<dim3(12, 64), 256, 0, stream>>>(x_bf, Wq_bf, Wk_bf, Wv_bf,
                                             q_ws, k_ws, vT);
  attn_kernel<<<dim3(16, 128), 256, 0, stream>>>(q_ws, k_ws, vT, E, attn);
  cvt_bf16<<<1024, 256, 0, stream>>>(Wo, Wo_bf, 262144);
  gemm_o<<<dim3(8, 64), 256, 0, stream>>>(attn, Wo_bf, outp);
}

// Round 8
// 274.820 us; speedup vs baseline: 1.0296x; 1.0296x over previous
//
#include <hip/hip_runtime.h>
#include <hip/hip_bf16.h>
#include <cstdint>
#include <cstddef>

typedef __hip_bfloat16 bf16;
typedef __attribute__((ext_vector_type(8))) __bf16 bf16x8;
typedef __attribute__((ext_vector_type(4))) float floatx4;

#define GPTR(p) ((const __attribute__((address_space(1))) void*)(p))
#define LPTR(p) ((__attribute__((address_space(3))) void*)(p))

// Native 2^x: exactly one v_exp_f32.  HIP's exp2f -> __ocml_exp2_f32 carries
// a denormal-range fixup (~5 VALU ops) in default mode -- measured r7: +30%
// absolute VALU time on the softmax chain.  native variant skips the fixup
// (softmax only needs flush-to-zero for huge-negative args).
extern "C" __device__ float __ocml_native_exp2_f32(float);
__device__ __forceinline__ float exp2n(float x) {
  return __ocml_native_exp2_f32(x);
}

__device__ __forceinline__ floatx4 mfma16(bf16x8 a, bf16x8 b, floatx4 c) {
  return __builtin_amdgcn_mfma_f32_16x16x32_bf16(a, b, c, 0, 0, 0);
}

// ---------------------------------------------------------------------------
// fp32 -> bf16 bulk convert
// ---------------------------------------------------------------------------
__global__ __launch_bounds__(256) void cvt_bf16(const float* __restrict__ in,
                                                bf16* __restrict__ out, int n4) {
  for (int i = blockIdx.x * 256 + threadIdx.x; i < n4; i += gridDim.x * 256) {
    float4 v = ((const float4*)in)[i];
    alignas(8) bf16 t[4] = {__float2bfloat16(v.x), __float2bfloat16(v.y),
                            __float2bfloat16(v.z), __float2bfloat16(v.w)};
    *(uint64_t*)(out + (size_t)i * 4) = *(const uint64_t*)t;
  }
}

// Fused Wq/Wk/Wv convert: one launch instead of three.
__global__ __launch_bounds__(256) void cvt_w3(const float* __restrict__ wq,
                                              const float* __restrict__ wk,
                                              const float* __restrict__ wv,
                                              bf16* __restrict__ oq,
                                              bf16* __restrict__ ok,
                                              bf16* __restrict__ ov) {
  int i = blockIdx.x * 256 + threadIdx.x;
  const float* in;
  bf16* out;
  int j;
  if (i < 262144) {
    in = wq; out = oq; j = i;
  } else if (i < 327680) {
    in = wk; out = ok; j = i - 262144;
  } else {
    in = wv; out = ov; j = i - 327680;
  }
  float4 v = ((const float4*)in)[j];
  alignas(8) bf16 t[4] = {__float2bfloat16(v.x), __float2bfloat16(v.y),
                          __float2bfloat16(v.z), __float2bfloat16(v.w)};
  *(uint64_t*)(out + (size_t)j * 4) = *(const uint64_t*)t;
}

// ---------------------------------------------------------------------------
// Fused QKV projection: A[8192,1024](bf16) @ [Wq;Wk;Wv](bf16)^T.
// q is scaled by 0.125 * log2(e): downstream softmax runs in exp2 domain.
// ---------------------------------------------------------------------------
__global__ __launch_bounds__(256) void gemm_qkv(
    const bf16* __restrict__ A, const bf16* __restrict__ Wq,
    const bf16* __restrict__ Wk, const bf16* __restrict__ Wv,
    bf16* __restrict__ qout, bf16* __restrict__ kout,
    bf16* __restrict__ vTout) {
  __shared__ alignas(16) bf16 As[128 * 32];
  __shared__ alignas(16) bf16 Bs[128 * 32];
  const int tid = threadIdx.x;
  const int lane = tid & 63;
  const int w = tid >> 6;
  const int wr = w >> 1, wc = w & 1;
  const int quad = lane >> 4, c = lane & 15;
  const int m0 = blockIdx.y * 128;
  const int nb = blockIdx.x;

  int mode, nloc;
  const bf16* Wp;
  if (nb < 8) {
    mode = 1; Wp = Wq + (size_t)nb * 128 * 1024; nloc = nb * 128;
  } else if (nb < 10) {
    mode = 2; Wp = Wk + (size_t)(nb - 8) * 128 * 1024; nloc = (nb - 8) * 128;
  } else {
    mode = 3; Wp = Wv + (size_t)(nb - 10) * 128 * 1024; nloc = (nb - 10) * 128;
  }

  const int i0 = tid, i1 = tid + 256;
  const bf16* ga0 = A + (size_t)(m0 + (i0 >> 2)) * 1024 + (i0 & 3) * 8;
  const bf16* ga1 = A + (size_t)(m0 + (i1 >> 2)) * 1024 + (i1 & 3) * 8;
  const bf16* gb0 = Wp + (size_t)(i0 >> 2) * 1024 + (i0 & 3) * 8;
  const bf16* gb1 = Wp + (size_t)(i1 >> 2) * 1024 + (i1 & 3) * 8;

  floatx4 acc[4][4] = {};

  for (int kt = 0; kt < 32; ++kt) {
    if (kt) __syncthreads();
    __builtin_amdgcn_global_load_lds(GPTR(ga0), LPTR(&As[i0 * 8]), 16, 0, 0);
    __builtin_amdgcn_global_load_lds(GPTR(ga1), LPTR(&As[i1 * 8]), 16, 0, 0);
    __builtin_amdgcn_global_load_lds(GPTR(gb0), LPTR(&Bs[i0 * 8]), 16, 0, 0);
    __builtin_amdgcn_global_load_lds(GPTR(gb1), LPTR(&Bs[i1 * 8]), 16, 0, 0);
    ga0 += 32; ga1 += 32; gb0 += 32; gb1 += 32;
    __syncthreads();
    bf16x8 af[4], bfr[4];
#pragma unroll
    for (int i = 0; i < 4; ++i)
      af[i] = *(const bf16x8*)&As[(wr * 64 + i * 16 + c) * 32 + quad * 8];
#pragma unroll
    for (int j = 0; j < 4; ++j)
      bfr[j] = *(const bf16x8*)&Bs[(wc * 64 + j * 16 + c) * 32 + quad * 8];
#pragma unroll
    for (int i = 0; i < 4; ++i)
#pragma unroll
      for (int j = 0; j < 4; ++j)
        acc[i][j] = mfma16(af[i], bfr[j], acc[i][j]);
  }

  if (mode == 3) {  // vT[((b*4+g)*64+d)*1024+t]: 4 consecutive t -> 8B store
#pragma unroll
    for (int i = 0; i < 4; ++i)
#pragma unroll
      for (int j = 0; j < 4; ++j) {
        int m = m0 + wr * 64 + i * 16 + quad * 4;
        int n = nloc + wc * 64 + j * 16 + c;
        int b = m >> 10, t = m & 1023, g = n >> 6, d = n & 63;
        alignas(8) bf16 tmp[4];
#pragma unroll
        for (int r = 0; r < 4; ++r) tmp[r] = __float2bfloat16(acc[i][j][r]);
        *(uint64_t*)(vTout + (((size_t)(b * 4 + g)) * 64 + d) * 1024 + t) =
            *(const uint64_t*)tmp;
      }
    return;
  }

  // 0.125 (1/sqrt(hd)) * 1.44269504 (log2 e): softmax in exp2 domain.
  const float scale = (mode == 1) ? 0.18033688f : 1.0f;
#pragma unroll
  for (int i = 0; i < 4; ++i)
#pragma unroll
    for (int j = 0; j < 4; ++j)
#pragma unroll
      for (int r = 0; r < 4; ++r) {
        int m = m0 + wr * 64 + i * 16 + quad * 4 + r;
        int n = nloc + wc * 64 + j * 16 + c;
        int b = m >> 10, t = m & 1023;
        bf16 v = __float2bfloat16(acc[i][j][r] * scale);
        if (mode == 1) {
          int h = n >> 6;
          qout[(((size_t)(b * 16 + h)) * 1024 + t) * 64 + (n & 63)] = v;
        } else {
          int g = n >> 6;
          kout[(((size_t)(b * 4 + g)) * 1024 + t) * 64 + (n & 63)] = v;
        }
      }
}

// ---------------------------------------------------------------------------
// O-projection: attn[8192,1024](bf16) @ Wo(bf16)^T -> fp32 d_out.
// ---------------------------------------------------------------------------
__global__ __launch_bounds__(256) void gemm_o(const bf16* __restrict__ A,
                                              const bf16* __restrict__ W,
                                              float* __restrict__ out) {
  __shared__ alignas(16) bf16 As[128 * 32];
  __shared__ alignas(16) bf16 Bs[128 * 32];
  const int tid = threadIdx.x;
  const int lane = tid & 63;
  const int w = tid >> 6;
  const int wr = w >> 1, wc = w & 1;
  const int quad = lane >> 4, c = lane & 15;
  const int m0 = blockIdx.y * 128, n0 = blockIdx.x * 128;

  const int i0 = tid, i1 = tid + 256;
  const bf16* ga0 = A + (size_t)(m0 + (i0 >> 2)) * 1024 + (i0 & 3) * 8;
  const bf16* ga1 = A + (size_t)(m0 + (i1 >> 2)) * 1024 + (i1 & 3) * 8;
  const bf16* gb0 = W + (size_t)(n0 + (i0 >> 2)) * 1024 + (i0 & 3) * 8;
  const bf16* gb1 = W + (size_t)(n0 + (i1 >> 2)) * 1024 + (i1 & 3) * 8;

  floatx4 acc[4][4] = {};

  for (int kt = 0; kt < 32; ++kt) {
    if (kt) __syncthreads();
    __builtin_amdgcn_global_load_lds(GPTR(ga0), LPTR(&As[i0 * 8]), 16, 0, 0);
    __builtin_amdgcn_global_load_lds(GPTR(ga1), LPTR(&As[i1 * 8]), 16, 0, 0);
    __builtin_amdgcn_global_load_lds(GPTR(gb0), LPTR(&Bs[i0 * 8]), 16, 0, 0);
    __builtin_amdgcn_global_load_lds(GPTR(gb1), LPTR(&Bs[i1 * 8]), 16, 0, 0);
    ga0 += 32; ga1 += 32; gb0 += 32; gb1 += 32;
    __syncthreads();
    bf16x8 af[4], bfr[4];
#pragma unroll
    for (int i = 0; i < 4; ++i)
      af[i] = *(const bf16x8*)&As[(wr * 64 + i * 16 + c) * 32 + quad * 8];
#pragma unroll
    for (int j = 0; j < 4; ++j)
      bfr[j] = *(const bf16x8*)&Bs[(wc * 64 + j * 16 + c) * 32 + quad * 8];
#pragma unroll
    for (int i = 0; i < 4; ++i)
#pragma unroll
      for (int j = 0; j < 4; ++j)
        acc[i][j] = mfma16(af[i], bfr[j], acc[i][j]);
  }

#pragma unroll
  for (int i = 0; i < 4; ++i)
#pragma unroll
    for (int j = 0; j < 4; ++j)
#pragma unroll
      for (int r = 0; r < 4; ++r) {
        int m = m0 + wr * 64 + i * 16 + quad * 4 + r;
        int n = n0 + wc * 64 + j * 16 + c;
        out[(size_t)m * 1024 + n] = acc[i][j][r];
      }
}

// ---------------------------------------------------------------------------
// Staged 64x64 bf16 tile with XOR-8 column-block swizzle (verified r0).
// ---------------------------------------------------------------------------
__device__ __forceinline__ void stage_tile_swz(const bf16* __restrict__ g,
                                               int gstride, bf16* __restrict__ dst,
                                               int tid) {
#pragma unroll
  for (int s = 0; s < 2; ++s) {
    int f = s * 256 + tid;
    int r = f >> 3, cb = f & 7;
    int cbg = cb ^ (r & 7);
    __builtin_amdgcn_global_load_lds(GPTR(g + (size_t)r * gstride + cbg * 8),
                                     LPTR(dst + f * 8), 16, 0, 0);
  }
}

__device__ __forceinline__ bf16x8 read_frag_swz(const bf16* __restrict__ tile,
                                                int row, int cb) {
  return *(const bf16x8*)&tile[row * 64 + ((cb ^ (row & 7)) * 8)];
}

// ---------------------------------------------------------------------------
// Flash attention, S^T = K.Q^T form.  Round-8 = r7 with ONE change:
// exp2f (OCML fixup path, ~5 VALU ops) -> __ocml_native_exp2_f32 (1 op).
// r7 isolated: XCD swizzle verified (FETCH 41.3->12.6 MB) but exp2f's
// denormal fixup added ~30% absolute VALU time -> net -10us.  This round
// keeps the swizzle + exp2 domain, restores the 1-op exp.
// LDS: qEl 33792 + K/P 9216 + V 8192 = 51200 -> 3 blocks/CU.
// ---------------------------------------------------------------------------
__global__ __launch_bounds__(256, 3) void attn_kernel(
    const bf16* __restrict__ q_ws, const bf16* __restrict__ k_ws,
    const bf16* __restrict__ vT, const float* __restrict__ E,
    bf16* __restrict__ out) {
  __shared__ alignas(16) bf16 qEl[64 * 264];  // bias table, rows lane-private
  __shared__ alignas(16) bf16 Ks[64 * 72];    // K tile (staged 64x64) / P rows
  __shared__ alignas(16) bf16 Vs[64 * 64];    // V^T tile
  const int tid = threadIdx.x;
  const int lane = tid & 63, w = tid >> 6;
  const int quad = lane >> 4, c = lane & 15;
  // XCD-chunked swizzle (bijective; verified r7: FETCH 41.3 -> 12.6 MB)
  const int phys = blockIdx.y * 16 + blockIdx.x;
  const int logical = (phys & 7) * 256 + (phys >> 3);
  const int bh = logical >> 4;
  const int b = bh >> 4, h = bh & 15, g = h >> 2;
  const int qb = (logical & 15) * 64 + w * 16;

  const bf16* qrow = q_ws + ((size_t)bh * 1024 + qb + c) * 64;
  bf16x8 qf0 = *(const bf16x8*)(qrow + quad * 8);
  bf16x8 qf1 = *(const bf16x8*)(qrow + 32 + quad * 8);

  // qE[qlocal][p] = q.E[p]  (wave's rows w*16..w*16+15; p in [0,254])
  for (int jn = 0; jn < 16; ++jn) {
    int er = jn * 16 + c;
    er = er > 254 ? 254 : er;
    const float* Ep = E + (size_t)er * 64;
    float4 e0 = *(const float4*)(Ep + quad * 8);
    float4 e1 = *(const float4*)(Ep + quad * 8 + 4);
    float4 e2 = *(const float4*)(Ep + 32 + quad * 8);
    float4 e3 = *(const float4*)(Ep + 32 + quad * 8 + 4);
    alignas(16) bf16 t0b[8] = {
        __float2bfloat16(e0.x), __float2bfloat16(e0.y), __float2bfloat16(e0.z),
        __float2bfloat16(e0.w), __float2bfloat16(e1.x), __float2bfloat16(e1.y),
        __float2bfloat16(e1.z), __float2bfloat16(e1.w)};
    alignas(16) bf16 t1b[8] = {
        __float2bfloat16(e2.x), __float2bfloat16(e2.y), __float2bfloat16(e2.z),
        __float2bfloat16(e2.w), __float2bfloat16(e3.x), __float2bfloat16(e3.y),
        __float2bfloat16(e3.z), __float2bfloat16(e3.w)};
    floatx4 a = {};
    a = mfma16(qf0, *(const bf16x8*)t0b, a);
    a = mfma16(qf1, *(const bf16x8*)t1b, a);
#pragma unroll
    for (int r = 0; r < 4; ++r)
      qEl[(w * 16 + quad * 4 + r) * 264 + jn * 16 + c] = __float2bfloat16(a[r]);
  }
  __syncthreads();  // qEl ready for all waves

  const bf16* rowE = qEl + (size_t)(w * 16 + c) * 264;
  bf16* rowP = Ks + (size_t)(w * 16 + c) * 72;
  float mrow = -1e30f, lpart = 0.f;
  floatx4 o[4] = {};
  const bf16* kbase = k_ws + (size_t)(b * 4 + g) * 1024 * 64;
  const bf16* vbase = vT + (size_t)(b * 4 + g) * 64 * 1024;
  const float blo = __bfloat162float(rowE[254]);
  const float bhi = __bfloat162float(rowE[0]);

  for (int t0 = 0; t0 < 1024; t0 += 64) {
    stage_tile_swz(kbase + (size_t)t0 * 64, 64, Ks, tid);
    stage_tile_swz(vbase + t0, 1024, Vs, tid);
    __syncthreads();  // A: staging landed
    floatx4 S[4];
#pragma unroll
    for (int j = 0; j < 4; ++j) {
      bf16x8 kf0 = read_frag_swz(Ks, j * 16 + c, quad);
      bf16x8 kf1 = read_frag_swz(Ks, j * 16 + c, quad + 4);
      floatx4 z = {};
      z = mfma16(kf0, qf0, z);
      S[j] = mfma16(kf1, qf1, z);
    }
    const int dlt0 = qb + c - t0;
    if (t0 <= qb - 190) {
#pragma unroll
      for (int j = 0; j < 4; ++j)
#pragma unroll
        for (int r = 0; r < 4; ++r) S[j][r] += blo;
    } else if (t0 >= qb + 142) {
#pragma unroll
      for (int j = 0; j < 4; ++j)
#pragma unroll
        for (int r = 0; r < 4; ++r) S[j][r] += bhi;
    } else {
#pragma unroll
      for (int j = 0; j < 4; ++j)
#pragma unroll
        for (int r = 0; r < 4; ++r) {
          int dlt = dlt0 - j * 16 - quad * 4 - r;
          dlt = dlt > 127 ? 127 : (dlt < -127 ? -127 : dlt);
          S[j][r] += __bfloat162float(rowE[dlt + 127]);
        }
    }
    // --- T13 defer-rescale online softmax (exp2 domain, native v_exp_f32)
    float mx = S[0][0];
#pragma unroll
    for (int j = 0; j < 4; ++j)
#pragma unroll
      for (int r = 0; r < 4; ++r) mx = fmaxf(mx, S[j][r]);
    if (__ballot(mx > mrow + 11.5f)) {
      // rare path (tile 0 + genuine max growth): full reduce + rescale
      float fm = fmaxf(mx, __shfl_xor(mx, 16, 64));
      fm = fmaxf(fm, __shfl_xor(fm, 32, 64));
      float nm = fmaxf(mrow, fm);
      float alpha = exp2n(mrow - nm);
      float av[4];
#pragma unroll
      for (int r = 0; r < 4; ++r) av[r] = __shfl(alpha, quad * 4 + r, 64);
#pragma unroll
      for (int jj = 0; jj < 4; ++jj)
#pragma unroll
        for (int r = 0; r < 4; ++r) o[jj][r] *= av[r];
      lpart *= alpha;
      mrow = nm;
    }
    float rs = 0.f;
#pragma unroll
    for (int j = 0; j < 4; ++j)
#pragma unroll
      for (int r = 0; r < 4; ++r) {
        float p = exp2n(S[j][r] - mrow);  // bounded by 2^11.5
        S[j][r] = p;
        rs += p;
      }
    lpart += rs;  // per-lane partial (this quad's kv slice); reduced at end
    __syncthreads();  // B: K frags consumed; Ks reusable as P
#pragma unroll
    for (int j = 0; j < 4; ++j) {
      alignas(8) bf16 tmp[4];
#pragma unroll
      for (int r = 0; r < 4; ++r) tmp[r] = __float2bfloat16(S[j][r]);
      *(uint64_t*)(rowP + j * 16 + quad * 4) = *(const uint64_t*)tmp;
    }
    __threadfence_block();
    __builtin_amdgcn_wave_barrier();
    bf16x8 pf0 = *(const bf16x8*)(rowP + quad * 8);
    bf16x8 pf1 = *(const bf16x8*)(rowP + 32 + quad * 8);
#pragma unroll
    for (int jj = 0; jj < 4; ++jj) {
      bf16x8 vf0 = read_frag_swz(Vs, jj * 16 + c, quad);
      bf16x8 vf1 = read_frag_swz(Vs, jj * 16 + c, quad + 4);
      o[jj] = mfma16(pf0, vf0, o[jj]);
      o[jj] = mfma16(pf1, vf1, o[jj]);
    }
    __syncthreads();  // C: P/V consumed; safe to restage
  }

  // one-time l reduction: per-lane quad partials -> row totals
  float lsum = lpart + __shfl_xor(lpart, 16, 64);
  lsum += __shfl_xor(lsum, 32, 64);
  float lr4[4];
#pragma unroll
  for (int r = 0; r < 4; ++r) lr4[r] = __shfl(lsum, quad * 4 + r, 64);
#pragma unroll
  for (int jj = 0; jj < 4; ++jj)
#pragma unroll
    for (int r = 0; r < 4; ++r) {
      int qi = qb + quad * 4 + r;
      out[(((size_t)b * 1024 + qi) * 16 + h) * 64 + jj * 16 + c] =
          __float2bfloat16(o[jj][r] / lr4[r]);
    }
}

// ---------------------------------------------------------------------------
// Memory plan (unchanged, proven):
//   d_out (32 MB fp32): [0,16M) q bf16 | [16M,32M) x_bf16.
//   ws: k 4MB @0 | vT 4MB @4M | attn 16MB @8M
//   Wq/Wk/Wv_bf @8M/10M/10.5M (attn region, dead before attn_kernel writes).
//   Wo_bf @0 (k region; converted AFTER attn_kernel consumed k).
// ---------------------------------------------------------------------------
extern "C" void kernel_launch(void* const* d_in, const int* in_sizes, int n_in,
                              void* d_out, int out_size, void* d_ws,
                              size_t ws_size, hipStream_t stream) {
  const float* x = (const float*)d_in[0];
  const float* Wq = (const float*)d_in[1];
  const float* Wk = (const float*)d_in[2];
  const float* Wv = (const float*)d_in[3];
  const float* Wo = (const float*)d_in[4];
  const float* E = (const float*)d_in[5];

  char* ws = (char*)d_ws;
  bf16* q_ws = (bf16*)d_out;                           // [0,16M) of d_out
  bf16* x_bf = (bf16*)((char*)d_out + (16ull << 20));  // [16M,32M) of d_out
  bf16* k_ws = (bf16*)(ws);
  bf16* vT = (bf16*)(ws + (4ull << 20));
  bf16* attn = (bf16*)(ws + (8ull << 20));
  bf16* Wq_bf = (bf16*)(ws + (8ull << 20));            // 2 MB   (attn region)
  bf16* Wk_bf = (bf16*)(ws + (10ull << 20));           // 0.5 MB (attn region)
  bf16* Wv_bf = (bf16*)(ws + (10ull << 20) + (512ull << 10));  // 0.5 MB
  bf16* Wo_bf = (bf16*)(ws);                           // 2 MB   (k region)
  float* outp = (float*)d_out;

  cvt_bf16<<<2048, 256, 0, stream>>>(x, x_bf, 2097152);
  cvt_w3<<<1536, 256, 0, stream>>>(Wq, Wk, Wv, Wq_bf, Wk_bf, Wv_bf);
  gemm_qkv<<<dim3(12, 64), 256, 0, stream>>>(x_bf, Wq_bf, Wk_bf, Wv_bf,
                                             q_ws, k_ws, vT);
  attn_kernel<<<dim3(16, 128), 256, 0, stream>>>(q_ws, k_ws, vT, E, attn);
  cvt_bf16<<<1024, 256, 0, stream>>>(Wo, Wo_bf, 262144);
  gemm_o<<<dim3(8, 64), 256, 0, stream>>>(attn, Wo_bf, outp);
}

// Round 9
// 268.302 us; speedup vs baseline: 1.0546x; 1.0243x over previous
//
#include <hip/hip_runtime.h>
#include <hip/hip_bf16.h>
#include <cstdint>
#include <cstddef>

typedef __hip_bfloat16 bf16;
typedef __attribute__((ext_vector_type(8))) __bf16 bf16x8;
typedef __attribute__((ext_vector_type(4))) float floatx4;

#define GPTR(p) ((const __attribute__((address_space(1))) void*)(p))
#define LPTR(p) ((__attribute__((address_space(3))) void*)(p))

// Native 2^x: exactly one v_exp_f32 (r8-verified: OCML exp2f's denormal
// fixup cost +30% absolute VALU on the softmax chain).
extern "C" __device__ float __ocml_native_exp2_f32(float);
__device__ __forceinline__ float exp2n(float x) {
  return __ocml_native_exp2_f32(x);
}

__device__ __forceinline__ floatx4 mfma16(bf16x8 a, bf16x8 b, floatx4 c) {
  return __builtin_amdgcn_mfma_f32_16x16x32_bf16(a, b, c, 0, 0, 0);
}

// ---------------------------------------------------------------------------
// fp32 -> bf16 bulk convert
// ---------------------------------------------------------------------------
__global__ __launch_bounds__(256) void cvt_bf16(const float* __restrict__ in,
                                                bf16* __restrict__ out, int n4) {
  for (int i = blockIdx.x * 256 + threadIdx.x; i < n4; i += gridDim.x * 256) {
    float4 v = ((const float4*)in)[i];
    alignas(8) bf16 t[4] = {__float2bfloat16(v.x), __float2bfloat16(v.y),
                            __float2bfloat16(v.z), __float2bfloat16(v.w)};
    *(uint64_t*)(out + (size_t)i * 4) = *(const uint64_t*)t;
  }
}

// Fused Wq/Wk/Wv convert: one launch instead of three.
__global__ __launch_bounds__(256) void cvt_w3(const float* __restrict__ wq,
                                              const float* __restrict__ wk,
                                              const float* __restrict__ wv,
                                              bf16* __restrict__ oq,
                                              bf16* __restrict__ ok,
                                              bf16* __restrict__ ov) {
  int i = blockIdx.x * 256 + threadIdx.x;
  const float* in;
  bf16* out;
  int j;
  if (i < 262144) {
    in = wq; out = oq; j = i;
  } else if (i < 327680) {
    in = wk; out = ok; j = i - 262144;
  } else {
    in = wv; out = ov; j = i - 327680;
  }
  float4 v = ((const float4*)in)[j];
  alignas(8) bf16 t[4] = {__float2bfloat16(v.x), __float2bfloat16(v.y),
                          __float2bfloat16(v.z), __float2bfloat16(v.w)};
  *(uint64_t*)(out + (size_t)j * 4) = *(const uint64_t*)t;
}

// ---------------------------------------------------------------------------
// 128-row x 64-col (BK=64) bf16 tile staging with XOR-8 chunk swizzle:
// LDS[r][cb] = G[r][cb ^ (r&7)], LDS dest linear (global_load_lds rule),
// read with the inverse XOR.  Kills the 8-way ds_read_b128 bank conflict
// of the row-stride-128B layout (same verified pattern as attn staging).
// ---------------------------------------------------------------------------
__device__ __forceinline__ void stage128_swz(const bf16* __restrict__ g,
                                             int gstride,
                                             bf16* __restrict__ dst, int tid) {
#pragma unroll
  for (int s = 0; s < 4; ++s) {
    int f = s * 256 + tid;
    int r = f >> 3, cb = f & 7;
    int cbg = cb ^ (r & 7);
    __builtin_amdgcn_global_load_lds(GPTR(g + (size_t)r * gstride + cbg * 8),
                                     LPTR(dst + f * 8), 16, 0, 0);
  }
}

__device__ __forceinline__ bf16x8 rd128_swz(const bf16* __restrict__ tile,
                                            int row, int ci) {
  return *(const bf16x8*)&tile[row * 64 + ((ci ^ (row & 7)) * 8)];
}

// ---------------------------------------------------------------------------
// Fused QKV projection: A[8192,1024](bf16) @ [Wq;Wk;Wv](bf16)^T.
// Round-9: BK=64 (32 barriers -> 16 per run), XOR-swizzled LDS (conflict-
// free ds_read_b128), XCD-chunked block swizzle (768 = 8 XCD x 8 m-panels
// x 12 nb: each 256KB A-panel fetched into exactly one XCD L2).
// q scaled by 0.125*log2e: softmax runs in exp2 domain.
// ---------------------------------------------------------------------------
__global__ __launch_bounds__(256) void gemm_qkv(
    const bf16* __restrict__ A, const bf16* __restrict__ Wq,
    const bf16* __restrict__ Wk, const bf16* __restrict__ Wv,
    bf16* __restrict__ qout, bf16* __restrict__ kout,
    bf16* __restrict__ vTout) {
  __shared__ alignas(16) bf16 As[128 * 64];
  __shared__ alignas(16) bf16 Bs[128 * 64];
  const int tid = threadIdx.x;
  const int lane = tid & 63;
  const int w = tid >> 6;
  const int wr = w >> 1, wc = w & 1;
  const int quad = lane >> 4, c = lane & 15;
  // XCD-chunk swizzle: phys%8 = XCD (verified r7); each XCD owns 8 m-panels.
  const int phys = blockIdx.y * 12 + blockIdx.x;
  const int ll = phys >> 3;
  const int m0 = ((phys & 7) * 8 + ll / 12) * 128;
  const int nb = ll % 12;

  int mode, nloc;
  const bf16* Wp;
  if (nb < 8) {
    mode = 1; Wp = Wq + (size_t)nb * 128 * 1024; nloc = nb * 128;
  } else if (nb < 10) {
    mode = 2; Wp = Wk + (size_t)(nb - 8) * 128 * 1024; nloc = (nb - 8) * 128;
  } else {
    mode = 3; Wp = Wv + (size_t)(nb - 10) * 128 * 1024; nloc = (nb - 10) * 128;
  }

  const bf16* pa = A + (size_t)m0 * 1024;
  const bf16* pb = Wp;

  floatx4 acc[4][4] = {};

  for (int kt = 0; kt < 16; ++kt) {
    if (kt) __syncthreads();
    stage128_swz(pa, 1024, As, tid);
    stage128_swz(pb, 1024, Bs, tid);
    pa += 64; pb += 64;
    __syncthreads();
#pragma unroll
    for (int kk = 0; kk < 2; ++kk) {
      bf16x8 af[4], bfr[4];
#pragma unroll
      for (int i = 0; i < 4; ++i)
        af[i] = rd128_swz(As, wr * 64 + i * 16 + c, kk * 4 + quad);
#pragma unroll
      for (int j = 0; j < 4; ++j)
        bfr[j] = rd128_swz(Bs, wc * 64 + j * 16 + c, kk * 4 + quad);
#pragma unroll
      for (int i = 0; i < 4; ++i)
#pragma unroll
        for (int j = 0; j < 4; ++j)
          acc[i][j] = mfma16(af[i], bfr[j], acc[i][j]);
    }
  }

  if (mode == 3) {  // vT[((b*4+g)*64+d)*1024+t]: 4 consecutive t -> 8B store
#pragma unroll
    for (int i = 0; i < 4; ++i)
#pragma unroll
      for (int j = 0; j < 4; ++j) {
        int m = m0 + wr * 64 + i * 16 + quad * 4;
        int n = nloc + wc * 64 + j * 16 + c;
        int b = m >> 10, t = m & 1023, g = n >> 6, d = n & 63;
        alignas(8) bf16 tmp[4];
#pragma unroll
        for (int r = 0; r < 4; ++r) tmp[r] = __float2bfloat16(acc[i][j][r]);
        *(uint64_t*)(vTout + (((size_t)(b * 4 + g)) * 64 + d) * 1024 + t) =
            *(const uint64_t*)tmp;
      }
    return;
  }

  // 0.125 (1/sqrt(hd)) * 1.44269504 (log2 e): softmax in exp2 domain.
  const float scale = (mode == 1) ? 0.18033688f : 1.0f;
#pragma unroll
  for (int i = 0; i < 4; ++i)
#pragma unroll
    for (int j = 0; j < 4; ++j)
#pragma unroll
      for (int r = 0; r < 4; ++r) {
        int m = m0 + wr * 64 + i * 16 + quad * 4 + r;
        int n = nloc + wc * 64 + j * 16 + c;
        int b = m >> 10, t = m & 1023;
        bf16 v = __float2bfloat16(acc[i][j][r] * scale);
        if (mode == 1) {
          int h = n >> 6;
          qout[(((size_t)(b * 16 + h)) * 1024 + t) * 64 + (n & 63)] = v;
        } else {
          int g = n >> 6;
          kout[(((size_t)(b * 4 + g)) * 1024 + t) * 64 + (n & 63)] = v;
        }
      }
}

// ---------------------------------------------------------------------------
// O-projection: attn[8192,1024](bf16) @ Wo(bf16)^T -> fp32 d_out.
// Same round-9 treatment: BK=64, XOR swizzle, XCD chunking (512 = 8x8x8).
// ---------------------------------------------------------------------------
__global__ __launch_bounds__(256) void gemm_o(const bf16* __restrict__ A,
                                              const bf16* __restrict__ W,
                                              float* __restrict__ out) {
  __shared__ alignas(16) bf16 As[128 * 64];
  __shared__ alignas(16) bf16 Bs[128 * 64];
  const int tid = threadIdx.x;
  const int lane = tid & 63;
  const int w = tid >> 6;
  const int wr = w >> 1, wc = w & 1;
  const int quad = lane >> 4, c = lane & 15;
  const int phys = blockIdx.y * 8 + blockIdx.x;
  const int ll = phys >> 3;
  const int m0 = ((phys & 7) * 8 + (ll >> 3)) * 128;
  const int n0 = (ll & 7) * 128;

  const bf16* pa = A + (size_t)m0 * 1024;
  const bf16* pb = W + (size_t)n0 * 1024;

  floatx4 acc[4][4] = {};

  for (int kt = 0; kt < 16; ++kt) {
    if (kt) __syncthreads();
    stage128_swz(pa, 1024, As, tid);
    stage128_swz(pb, 1024, Bs, tid);
    pa += 64; pb += 64;
    __syncthreads();
#pragma unroll
    for (int kk = 0; kk < 2; ++kk) {
      bf16x8 af[4], bfr[4];
#pragma unroll
      for (int i = 0; i < 4; ++i)
        af[i] = rd128_swz(As, wr * 64 + i * 16 + c, kk * 4 + quad);
#pragma unroll
      for (int j = 0; j < 4; ++j)
        bfr[j] = rd128_swz(Bs, wc * 64 + j * 16 + c, kk * 4 + quad);
#pragma unroll
      for (int i = 0; i < 4; ++i)
#pragma unroll
        for (int j = 0; j < 4; ++j)
          acc[i][j] = mfma16(af[i], bfr[j], acc[i][j]);
    }
  }

#pragma unroll
  for (int i = 0; i < 4; ++i)
#pragma unroll
    for (int j = 0; j < 4; ++j)
#pragma unroll
      for (int r = 0; r < 4; ++r) {
        int m = m0 + wr * 64 + i * 16 + quad * 4 + r;
        int n = n0 + wc * 64 + j * 16 + c;
        out[(size_t)m * 1024 + n] = acc[i][j][r];
      }
}

// ---------------------------------------------------------------------------
// Staged 64x64 bf16 tile with XOR-8 column-block swizzle (verified r0).
// ---------------------------------------------------------------------------
__device__ __forceinline__ void stage_tile_swz(const bf16* __restrict__ g,
                                               int gstride, bf16* __restrict__ dst,
                                               int tid) {
#pragma unroll
  for (int s = 0; s < 2; ++s) {
    int f = s * 256 + tid;
    int r = f >> 3, cb = f & 7;
    int cbg = cb ^ (r & 7);
    __builtin_amdgcn_global_load_lds(GPTR(g + (size_t)r * gstride + cbg * 8),
                                     LPTR(dst + f * 8), 16, 0, 0);
  }
}

__device__ __forceinline__ bf16x8 read_frag_swz(const bf16* __restrict__ tile,
                                                int row, int cb) {
  return *(const bf16x8*)&tile[row * 64 + ((cb ^ (row & 7)) * 8)];
}

// ---------------------------------------------------------------------------
// Flash attention, S^T = K.Q^T form.  FROZEN at round-8 best (126.1us):
// XCD swizzle (FETCH 41.3->12.6 MB verified), exp2-domain softmax with
// native v_exp_f32, T13 defer-rescale, per-lane partial l.
// LDS: qEl 33792 + K/P 9216 + V 8192 = 51200 -> 3 blocks/CU.
// ---------------------------------------------------------------------------
__global__ __launch_bounds__(256, 3) void attn_kernel(
    const bf16* __restrict__ q_ws, const bf16* __restrict__ k_ws,
    const bf16* __restrict__ vT, const float* __restrict__ E,
    bf16* __restrict__ out) {
  __shared__ alignas(16) bf16 qEl[64 * 264];  // bias table, rows lane-private
  __shared__ alignas(16) bf16 Ks[64 * 72];    // K tile (staged 64x64) / P rows
  __shared__ alignas(16) bf16 Vs[64 * 64];    // V^T tile
  const int tid = threadIdx.x;
  const int lane = tid & 63, w = tid >> 6;
  const int quad = lane >> 4, c = lane & 15;
  const int phys = blockIdx.y * 16 + blockIdx.x;
  const int logical = (phys & 7) * 256 + (phys >> 3);
  const int bh = logical >> 4;
  const int b = bh >> 4, h = bh & 15, g = h >> 2;
  const int qb = (logical & 15) * 64 + w * 16;

  const bf16* qrow = q_ws + ((size_t)bh * 1024 + qb + c) * 64;
  bf16x8 qf0 = *(const bf16x8*)(qrow + quad * 8);
  bf16x8 qf1 = *(const bf16x8*)(qrow + 32 + quad * 8);

  // qE[qlocal][p] = q.E[p]  (wave's rows w*16..w*16+15; p in [0,254])
  for (int jn = 0; jn < 16; ++jn) {
    int er = jn * 16 + c;
    er = er > 254 ? 254 : er;
    const float* Ep = E + (size_t)er * 64;
    float4 e0 = *(const float4*)(Ep + quad * 8);
    float4 e1 = *(const float4*)(Ep + quad * 8 + 4);
    float4 e2 = *(const float4*)(Ep + 32 + quad * 8);
    float4 e3 = *(const float4*)(Ep + 32 + quad * 8 + 4);
    alignas(16) bf16 t0b[8] = {
        __float2bfloat16(e0.x), __float2bfloat16(e0.y), __float2bfloat16(e0.z),
        __float2bfloat16(e0.w), __float2bfloat16(e1.x), __float2bfloat16(e1.y),
        __float2bfloat16(e1.z), __float2bfloat16(e1.w)};
    alignas(16) bf16 t1b[8] = {
        __float2bfloat16(e2.x), __float2bfloat16(e2.y), __float2bfloat16(e2.z),
        __float2bfloat16(e2.w), __float2bfloat16(e3.x), __float2bfloat16(e3.y),
        __float2bfloat16(e3.z), __float2bfloat16(e3.w)};
    floatx4 a = {};
    a = mfma16(qf0, *(const bf16x8*)t0b, a);
    a = mfma16(qf1, *(const bf16x8*)t1b, a);
#pragma unroll
    for (int r = 0; r < 4; ++r)
      qEl[(w * 16 + quad * 4 + r) * 264 + jn * 16 + c] = __float2bfloat16(a[r]);
  }
  __syncthreads();  // qEl ready for all waves

  const bf16* rowE = qEl + (size_t)(w * 16 + c) * 264;
  bf16* rowP = Ks + (size_t)(w * 16 + c) * 72;
  float mrow = -1e30f, lpart = 0.f;
  floatx4 o[4] = {};
  const bf16* kbase = k_ws + (size_t)(b * 4 + g) * 1024 * 64;
  const bf16* vbase = vT + (size_t)(b * 4 + g) * 64 * 1024;
  const float blo = __bfloat162float(rowE[254]);
  const float bhi = __bfloat162float(rowE[0]);

  for (int t0 = 0; t0 < 1024; t0 += 64) {
    stage_tile_swz(kbase + (size_t)t0 * 64, 64, Ks, tid);
    stage_tile_swz(vbase + t0, 1024, Vs, tid);
    __syncthreads();  // A: staging landed
    floatx4 S[4];
#pragma unroll
    for (int j = 0; j < 4; ++j) {
      bf16x8 kf0 = read_frag_swz(Ks, j * 16 + c, quad);
      bf16x8 kf1 = read_frag_swz(Ks, j * 16 + c, quad + 4);
      floatx4 z = {};
      z = mfma16(kf0, qf0, z);
      S[j] = mfma16(kf1, qf1, z);
    }
    const int dlt0 = qb + c - t0;
    if (t0 <= qb - 190) {
#pragma unroll
      for (int j = 0; j < 4; ++j)
#pragma unroll
        for (int r = 0; r < 4; ++r) S[j][r] += blo;
    } else if (t0 >= qb + 142) {
#pragma unroll
      for (int j = 0; j < 4; ++j)
#pragma unroll
        for (int r = 0; r < 4; ++r) S[j][r] += bhi;
    } else {
#pragma unroll
      for (int j = 0; j < 4; ++j)
#pragma unroll
        for (int r = 0; r < 4; ++r) {
          int dlt = dlt0 - j * 16 - quad * 4 - r;
          dlt = dlt > 127 ? 127 : (dlt < -127 ? -127 : dlt);
          S[j][r] += __bfloat162float(rowE[dlt + 127]);
        }
    }
    // --- T13 defer-rescale online softmax (exp2 domain, native v_exp_f32)
    float mx = S[0][0];
#pragma unroll
    for (int j = 0; j < 4; ++j)
#pragma unroll
      for (int r = 0; r < 4; ++r) mx = fmaxf(mx, S[j][r]);
    if (__ballot(mx > mrow + 11.5f)) {
      // rare path (tile 0 + genuine max growth): full reduce + rescale
      float fm = fmaxf(mx, __shfl_xor(mx, 16, 64));
      fm = fmaxf(fm, __shfl_xor(fm, 32, 64));
      float nm = fmaxf(mrow, fm);
      float alpha = exp2n(mrow - nm);
      float av[4];
#pragma unroll
      for (int r = 0; r < 4; ++r) av[r] = __shfl(alpha, quad * 4 + r, 64);
#pragma unroll
      for (int jj = 0; jj < 4; ++jj)
#pragma unroll
        for (int r = 0; r < 4; ++r) o[jj][r] *= av[r];
      lpart *= alpha;
      mrow = nm;
    }
    float rs = 0.f;
#pragma unroll
    for (int j = 0; j < 4; ++j)
#pragma unroll
      for (int r = 0; r < 4; ++r) {
        float p = exp2n(S[j][r] - mrow);  // bounded by 2^11.5
        S[j][r] = p;
        rs += p;
      }
    lpart += rs;  // per-lane partial (this quad's kv slice); reduced at end
    __syncthreads();  // B: K frags consumed; Ks reusable as P
#pragma unroll
    for (int j = 0; j < 4; ++j) {
      alignas(8) bf16 tmp[4];
#pragma unroll
      for (int r = 0; r < 4; ++r) tmp[r] = __float2bfloat16(S[j][r]);
      *(uint64_t*)(rowP + j * 16 + quad * 4) = *(const uint64_t*)tmp;
    }
    __threadfence_block();
    __builtin_amdgcn_wave_barrier();
    bf16x8 pf0 = *(const bf16x8*)(rowP + quad * 8);
    bf16x8 pf1 = *(const bf16x8*)(rowP + 32 + quad * 8);
#pragma unroll
    for (int jj = 0; jj < 4; ++jj) {
      bf16x8 vf0 = read_frag_swz(Vs, jj * 16 + c, quad);
      bf16x8 vf1 = read_frag_swz(Vs, jj * 16 + c, quad + 4);
      o[jj] = mfma16(pf0, vf0, o[jj]);
      o[jj] = mfma16(pf1, vf1, o[jj]);
    }
    __syncthreads();  // C: P/V consumed; safe to restage
  }

  // one-time l reduction: per-lane quad partials -> row totals
  float lsum = lpart + __shfl_xor(lpart, 16, 64);
  lsum += __shfl_xor(lsum, 32, 64);
  float lr4[4];
#pragma unroll
  for (int r = 0; r < 4; ++r) lr4[r] = __shfl(lsum, quad * 4 + r, 64);
#pragma unroll
  for (int jj = 0; jj < 4; ++jj)
#pragma unroll
    for (int r = 0; r < 4; ++r) {
      int qi = qb + quad * 4 + r;
      out[(((size_t)b * 1024 + qi) * 16 + h) * 64 + jj * 16 + c] =
          __float2bfloat16(o[jj][r] / lr4[r]);
    }
}

// ---------------------------------------------------------------------------
// Memory plan (unchanged, proven):
//   d_out (32 MB fp32): [0,16M) q bf16 | [16M,32M) x_bf16.
//   ws: k 4MB @0 | vT 4MB @4M | attn 16MB @8M
//   Wq/Wk/Wv_bf @8M/10M/10.5M (attn region, dead before attn_kernel writes).
//   Wo_bf @0 (k region; converted AFTER attn_kernel consumed k).
// ---------------------------------------------------------------------------
extern "C" void kernel_launch(void* const* d_in, const int* in_sizes, int n_in,
                              void* d_out, int out_size, void* d_ws,
                              size_t ws_size, hipStream_t stream) {
  const float* x = (const float*)d_in[0];
  const float* Wq = (const float*)d_in[1];
  const float* Wk = (const float*)d_in[2];
  const float* Wv = (const float*)d_in[3];
  const float* Wo = (const float*)d_in[4];
  const float* E = (const float*)d_in[5];

  char* ws = (char*)d_ws;
  bf16* q_ws = (bf16*)d_out;                           // [0,16M) of d_out
  bf16* x_bf = (bf16*)((char*)d_out + (16ull << 20));  // [16M,32M) of d_out
  bf16* k_ws = (bf16*)(ws);
  bf16* vT = (bf16*)(ws + (4ull << 20));
  bf16* attn = (bf16*)(ws + (8ull << 20));
  bf16* Wq_bf = (bf16*)(ws + (8ull << 20));            // 2 MB   (attn region)
  bf16* Wk_bf = (bf16*)(ws + (10ull << 20));           // 0.5 MB (attn region)
  bf16* Wv_bf = (bf16*)(ws + (10ull << 20) + (512ull << 10));  // 0.5 MB
  bf16* Wo_bf = (bf16*)(ws);                           // 2 MB   (k region)
  float* outp = (float*)d_out;

  cvt_bf16<<<2048, 256, 0, stream>>>(x, x_bf, 2097152);
  cvt_w3<<<1536, 256, 0, stream>>>(Wq, Wk, Wv, Wq_bf, Wk_bf, Wv_bf);
  gemm_qkv<<<dim3(12, 64), 256, 0, stream>>>(x_bf, Wq_bf, Wk_bf, Wv_bf,
                                             q_ws, k_ws, vT);
  attn_kernel<<<dim3(16, 128), 256, 0, stream>>>(q_ws, k_ws, vT, E, attn);
  cvt_bf16<<<1024, 256, 0, stream>>>(Wo, Wo_bf, 262144);
  gemm_o<<<dim3(8, 64), 256, 0, stream>>>(attn, Wo_bf, outp);
}

// Round 10
// 259.893 us; speedup vs baseline: 1.0887x; 1.0324x over previous
//
#include <hip/hip_runtime.h>
#include <hip/hip_bf16.h>
#include <cstdint>
#include <cstddef>

typedef __hip_bfloat16 bf16;
typedef __attribute__((ext_vector_type(8))) __bf16 bf16x8;
typedef __attribute__((ext_vector_type(4))) float floatx4;

#define GPTR(p) ((const __attribute__((address_space(1))) void*)(p))
#define LPTR(p) ((__attribute__((address_space(3))) void*)(p))

// Native 2^x: exactly one v_exp_f32 (r8-verified: OCML exp2f's denormal
// fixup cost +30% absolute VALU on the softmax chain).
extern "C" __device__ float __ocml_native_exp2_f32(float);
__device__ __forceinline__ float exp2n(float x) {
  return __ocml_native_exp2_f32(x);
}

__device__ __forceinline__ floatx4 mfma16(bf16x8 a, bf16x8 b, floatx4 c) {
  return __builtin_amdgcn_mfma_f32_16x16x32_bf16(a, b, c, 0, 0, 0);
}

__device__ __forceinline__ void cvt4(const float* __restrict__ in,
                                     bf16* __restrict__ out, int i) {
  float4 v = ((const float4*)in)[i];
  alignas(8) bf16 t[4] = {__float2bfloat16(v.x), __float2bfloat16(v.y),
                          __float2bfloat16(v.z), __float2bfloat16(v.w)};
  *(uint64_t*)(out + (size_t)i * 4) = *(const uint64_t*)t;
}

// ---------------------------------------------------------------------------
// fp32 -> bf16 bulk convert (fallback path for Wo)
// ---------------------------------------------------------------------------
__global__ __launch_bounds__(256) void cvt_bf16(const float* __restrict__ in,
                                                bf16* __restrict__ out, int n4) {
  for (int i = blockIdx.x * 256 + threadIdx.x; i < n4; i += gridDim.x * 256) {
    cvt4(in, out, i);
  }
}

// ---------------------------------------------------------------------------
// Round-10: ALL input conversions in ONE launch (was 2-3 launches).
// Partition: blocks [0,2048) = x (grid-stride, 2097152 f4);
//            [2048,3584) = Wq/Wk/Wv (one f4/thread);
//            [3584,4608) = Wo (only launched when ws has a safe early home).
// ---------------------------------------------------------------------------
__global__ __launch_bounds__(256) void cvt_all(
    const float* __restrict__ x, const float* __restrict__ wq,
    const float* __restrict__ wk, const float* __restrict__ wv,
    const float* __restrict__ wo, bf16* __restrict__ ox,
    bf16* __restrict__ oq, bf16* __restrict__ ok, bf16* __restrict__ ov,
    bf16* __restrict__ owo) {
  const int bid = blockIdx.x;
  if (bid < 2048) {
    for (int i = bid * 256 + threadIdx.x; i < 2097152; i += 2048 * 256)
      cvt4(x, ox, i);
  } else if (bid < 3584) {
    int i = (bid - 2048) * 256 + threadIdx.x;  // 0..393215
    if (i < 262144) {
      cvt4(wq, oq, i);
    } else if (i < 327680) {
      cvt4(wk, ok, i - 262144);
    } else {
      cvt4(wv, ov, i - 327680);
    }
  } else {
    cvt4(wo, owo, (bid - 3584) * 256 + threadIdx.x);  // 262144 f4
  }
}

// ---------------------------------------------------------------------------
// 128-row x 64-col (BK=64) bf16 tile staging with XOR-8 chunk swizzle
// (r9-verified: conflict-free ds_read_b128, linear LDS dest per gload rule).
// ---------------------------------------------------------------------------
__device__ __forceinline__ void stage128_swz(const bf16* __restrict__ g,
                                             int gstride,
                                             bf16* __restrict__ dst, int tid) {
#pragma unroll
  for (int s = 0; s < 4; ++s) {
    int f = s * 256 + tid;
    int r = f >> 3, cb = f & 7;
    int cbg = cb ^ (r & 7);
    __builtin_amdgcn_global_load_lds(GPTR(g + (size_t)r * gstride + cbg * 8),
                                     LPTR(dst + f * 8), 16, 0, 0);
  }
}

__device__ __forceinline__ bf16x8 rd128_swz(const bf16* __restrict__ tile,
                                            int row, int ci) {
  return *(const bf16x8*)&tile[row * 64 + ((ci ^ (row & 7)) * 8)];
}

// ---------------------------------------------------------------------------
// Fused QKV projection (frozen at r9): BK=64, XOR-swizzled LDS, XCD-chunked
// block swizzle.  q scaled by 0.125*log2e (exp2-domain softmax downstream).
// ---------------------------------------------------------------------------
__global__ __launch_bounds__(256) void gemm_qkv(
    const bf16* __restrict__ A, const bf16* __restrict__ Wq,
    const bf16* __restrict__ Wk, const bf16* __restrict__ Wv,
    bf16* __restrict__ qout, bf16* __restrict__ kout,
    bf16* __restrict__ vTout) {
  __shared__ alignas(16) bf16 As[128 * 64];
  __shared__ alignas(16) bf16 Bs[128 * 64];
  const int tid = threadIdx.x;
  const int lane = tid & 63;
  const int w = tid >> 6;
  const int wr = w >> 1, wc = w & 1;
  const int quad = lane >> 4, c = lane & 15;
  const int phys = blockIdx.y * 12 + blockIdx.x;
  const int ll = phys >> 3;
  const int m0 = ((phys & 7) * 8 + ll / 12) * 128;
  const int nb = ll % 12;

  int mode, nloc;
  const bf16* Wp;
  if (nb < 8) {
    mode = 1; Wp = Wq + (size_t)nb * 128 * 1024; nloc = nb * 128;
  } else if (nb < 10) {
    mode = 2; Wp = Wk + (size_t)(nb - 8) * 128 * 1024; nloc = (nb - 8) * 128;
  } else {
    mode = 3; Wp = Wv + (size_t)(nb - 10) * 128 * 1024; nloc = (nb - 10) * 128;
  }

  const bf16* pa = A + (size_t)m0 * 1024;
  const bf16* pb = Wp;

  floatx4 acc[4][4] = {};

  for (int kt = 0; kt < 16; ++kt) {
    if (kt) __syncthreads();
    stage128_swz(pa, 1024, As, tid);
    stage128_swz(pb, 1024, Bs, tid);
    pa += 64; pb += 64;
    __syncthreads();
#pragma unroll
    for (int kk = 0; kk < 2; ++kk) {
      bf16x8 af[4], bfr[4];
#pragma unroll
      for (int i = 0; i < 4; ++i)
        af[i] = rd128_swz(As, wr * 64 + i * 16 + c, kk * 4 + quad);
#pragma unroll
      for (int j = 0; j < 4; ++j)
        bfr[j] = rd128_swz(Bs, wc * 64 + j * 16 + c, kk * 4 + quad);
#pragma unroll
      for (int i = 0; i < 4; ++i)
#pragma unroll
        for (int j = 0; j < 4; ++j)
          acc[i][j] = mfma16(af[i], bfr[j], acc[i][j]);
    }
  }

  if (mode == 3) {  // vT[((b*4+g)*64+d)*1024+t]: 4 consecutive t -> 8B store
#pragma unroll
    for (int i = 0; i < 4; ++i)
#pragma unroll
      for (int j = 0; j < 4; ++j) {
        int m = m0 + wr * 64 + i * 16 + quad * 4;
        int n = nloc + wc * 64 + j * 16 + c;
        int b = m >> 10, t = m & 1023, g = n >> 6, d = n & 63;
        alignas(8) bf16 tmp[4];
#pragma unroll
        for (int r = 0; r < 4; ++r) tmp[r] = __float2bfloat16(acc[i][j][r]);
        *(uint64_t*)(vTout + (((size_t)(b * 4 + g)) * 64 + d) * 1024 + t) =
            *(const uint64_t*)tmp;
      }
    return;
  }

  // 0.125 (1/sqrt(hd)) * 1.44269504 (log2 e): softmax in exp2 domain.
  const float scale = (mode == 1) ? 0.18033688f : 1.0f;
#pragma unroll
  for (int i = 0; i < 4; ++i)
#pragma unroll
    for (int j = 0; j < 4; ++j)
#pragma unroll
      for (int r = 0; r < 4; ++r) {
        int m = m0 + wr * 64 + i * 16 + quad * 4 + r;
        int n = nloc + wc * 64 + j * 16 + c;
        int b = m >> 10, t = m & 1023;
        bf16 v = __float2bfloat16(acc[i][j][r] * scale);
        if (mode == 1) {
          int h = n >> 6;
          qout[(((size_t)(b * 16 + h)) * 1024 + t) * 64 + (n & 63)] = v;
        } else {
          int g = n >> 6;
          kout[(((size_t)(b * 4 + g)) * 1024 + t) * 64 + (n & 63)] = v;
        }
      }
}

// ---------------------------------------------------------------------------
// O-projection (frozen at r9): BK=64, XOR swizzle, XCD chunking.
// ---------------------------------------------------------------------------
__global__ __launch_bounds__(256) void gemm_o(const bf16* __restrict__ A,
                                              const bf16* __restrict__ W,
                                              float* __restrict__ out) {
  __shared__ alignas(16) bf16 As[128 * 64];
  __shared__ alignas(16) bf16 Bs[128 * 64];
  const int tid = threadIdx.x;
  const int lane = tid & 63;
  const int w = tid >> 6;
  const int wr = w >> 1, wc = w & 1;
  const int quad = lane >> 4, c = lane & 15;
  const int phys = blockIdx.y * 8 + blockIdx.x;
  const int ll = phys >> 3;
  const int m0 = ((phys & 7) * 8 + (ll >> 3)) * 128;
  const int n0 = (ll & 7) * 128;

  const bf16* pa = A + (size_t)m0 * 1024;
  const bf16* pb = W + (size_t)n0 * 1024;

  floatx4 acc[4][4] = {};

  for (int kt = 0; kt < 16; ++kt) {
    if (kt) __syncthreads();
    stage128_swz(pa, 1024, As, tid);
    stage128_swz(pb, 1024, Bs, tid);
    pa += 64; pb += 64;
    __syncthreads();
#pragma unroll
    for (int kk = 0; kk < 2; ++kk) {
      bf16x8 af[4], bfr[4];
#pragma unroll
      for (int i = 0; i < 4; ++i)
        af[i] = rd128_swz(As, wr * 64 + i * 16 + c, kk * 4 + quad);
#pragma unroll
      for (int j = 0; j < 4; ++j)
        bfr[j] = rd128_swz(Bs, wc * 64 + j * 16 + c, kk * 4 + quad);
#pragma unroll
      for (int i = 0; i < 4; ++i)
#pragma unroll
        for (int j = 0; j < 4; ++j)
          acc[i][j] = mfma16(af[i], bfr[j], acc[i][j]);
    }
  }

#pragma unroll
  for (int i = 0; i < 4; ++i)
#pragma unroll
    for (int j = 0; j < 4; ++j)
#pragma unroll
      for (int r = 0; r < 4; ++r) {
        int m = m0 + wr * 64 + i * 16 + quad * 4 + r;
        int n = n0 + wc * 64 + j * 16 + c;
        out[(size_t)m * 1024 + n] = acc[i][j][r];
      }
}

// ---------------------------------------------------------------------------
// Staged 64x64 bf16 tile with XOR-8 column-block swizzle (verified r0).
// ---------------------------------------------------------------------------
__device__ __forceinline__ void stage_tile_swz(const bf16* __restrict__ g,
                                               int gstride, bf16* __restrict__ dst,
                                               int tid) {
#pragma unroll
  for (int s = 0; s < 2; ++s) {
    int f = s * 256 + tid;
    int r = f >> 3, cb = f & 7;
    int cbg = cb ^ (r & 7);
    __builtin_amdgcn_global_load_lds(GPTR(g + (size_t)r * gstride + cbg * 8),
                                     LPTR(dst + f * 8), 16, 0, 0);
  }
}

__device__ __forceinline__ bf16x8 read_frag_swz(const bf16* __restrict__ tile,
                                                int row, int cb) {
  return *(const bf16x8*)&tile[row * 64 + ((cb ^ (row & 7)) * 8)];
}

// ---------------------------------------------------------------------------
// Flash attention (structure frozen at r8 best: XCD swizzle FETCH 41->12.6MB,
// exp2-domain + native v_exp_f32, T13 defer-rescale, per-lane partial l).
// Round-10 deltas only: (a) ONE division per lane (reciprocal broadcast
// instead of 16 divides), (b) T5 setprio(1) around QK and PV MFMA clusters
// (3 independent blocks/CU at different phases = m191's positive regime).
// LDS: qEl 33792 + K/P 9216 + V 8192 = 51200 -> 3 blocks/CU.
// ---------------------------------------------------------------------------
__global__ __launch_bounds__(256, 3) void attn_kernel(
    const bf16* __restrict__ q_ws, const bf16* __restrict__ k_ws,
    const bf16* __restrict__ vT, const float* __restrict__ E,
    bf16* __restrict__ out) {
  __shared__ alignas(16) bf16 qEl[64 * 264];  // bias table, rows lane-private
  __shared__ alignas(16) bf16 Ks[64 * 72];    // K tile (staged 64x64) / P rows
  __shared__ alignas(16) bf16 Vs[64 * 64];    // V^T tile
  const int tid = threadIdx.x;
  const int lane = tid & 63, w = tid >> 6;
  const int quad = lane >> 4, c = lane & 15;
  const int phys = blockIdx.y * 16 + blockIdx.x;
  const int logical = (phys & 7) * 256 + (phys >> 3);
  const int bh = logical >> 4;
  const int b = bh >> 4, h = bh & 15, g = h >> 2;
  const int qb = (logical & 15) * 64 + w * 16;

  const bf16* qrow = q_ws + ((size_t)bh * 1024 + qb + c) * 64;
  bf16x8 qf0 = *(const bf16x8*)(qrow + quad * 8);
  bf16x8 qf1 = *(const bf16x8*)(qrow + 32 + quad * 8);

  // qE[qlocal][p] = q.E[p]  (wave's rows w*16..w*16+15; p in [0,254])
  for (int jn = 0; jn < 16; ++jn) {
    int er = jn * 16 + c;
    er = er > 254 ? 254 : er;
    const float* Ep = E + (size_t)er * 64;
    float4 e0 = *(const float4*)(Ep + quad * 8);
    float4 e1 = *(const float4*)(Ep + quad * 8 + 4);
    float4 e2 = *(const float4*)(Ep + 32 + quad * 8);
    float4 e3 = *(const float4*)(Ep + 32 + quad * 8 + 4);
    alignas(16) bf16 t0b[8] = {
        __float2bfloat16(e0.x), __float2bfloat16(e0.y), __float2bfloat16(e0.z),
        __float2bfloat16(e0.w), __float2bfloat16(e1.x), __float2bfloat16(e1.y),
        __float2bfloat16(e1.z), __float2bfloat16(e1.w)};
    alignas(16) bf16 t1b[8] = {
        __float2bfloat16(e2.x), __float2bfloat16(e2.y), __float2bfloat16(e2.z),
        __float2bfloat16(e2.w), __float2bfloat16(e3.x), __float2bfloat16(e3.y),
        __float2bfloat16(e3.z), __float2bfloat16(e3.w)};
    floatx4 a = {};
    a = mfma16(qf0, *(const bf16x8*)t0b, a);
    a = mfma16(qf1, *(const bf16x8*)t1b, a);
#pragma unroll
    for (int r = 0; r < 4; ++r)
      qEl[(w * 16 + quad * 4 + r) * 264 + jn * 16 + c] = __float2bfloat16(a[r]);
  }
  __syncthreads();  // qEl ready for all waves

  const bf16* rowE = qEl + (size_t)(w * 16 + c) * 264;
  bf16* rowP = Ks + (size_t)(w * 16 + c) * 72;
  float mrow = -1e30f, lpart = 0.f;
  floatx4 o[4] = {};
  const bf16* kbase = k_ws + (size_t)(b * 4 + g) * 1024 * 64;
  const bf16* vbase = vT + (size_t)(b * 4 + g) * 64 * 1024;
  const float blo = __bfloat162float(rowE[254]);
  const float bhi = __bfloat162float(rowE[0]);

  for (int t0 = 0; t0 < 1024; t0 += 64) {
    stage_tile_swz(kbase + (size_t)t0 * 64, 64, Ks, tid);
    stage_tile_swz(vbase + t0, 1024, Vs, tid);
    __syncthreads();  // A: staging landed
    floatx4 S[4];
    __builtin_amdgcn_s_setprio(1);
#pragma unroll
    for (int j = 0; j < 4; ++j) {
      bf16x8 kf0 = read_frag_swz(Ks, j * 16 + c, quad);
      bf16x8 kf1 = read_frag_swz(Ks, j * 16 + c, quad + 4);
      floatx4 z = {};
      z = mfma16(kf0, qf0, z);
      S[j] = mfma16(kf1, qf1, z);
    }
    __builtin_amdgcn_s_setprio(0);
    const int dlt0 = qb + c - t0;
    if (t0 <= qb - 190) {
#pragma unroll
      for (int j = 0; j < 4; ++j)
#pragma unroll
        for (int r = 0; r < 4; ++r) S[j][r] += blo;
    } else if (t0 >= qb + 142) {
#pragma unroll
      for (int j = 0; j < 4; ++j)
#pragma unroll
        for (int r = 0; r < 4; ++r) S[j][r] += bhi;
    } else {
#pragma unroll
      for (int j = 0; j < 4; ++j)
#pragma unroll
        for (int r = 0; r < 4; ++r) {
          int dlt = dlt0 - j * 16 - quad * 4 - r;
          dlt = dlt > 127 ? 127 : (dlt < -127 ? -127 : dlt);
          S[j][r] += __bfloat162float(rowE[dlt + 127]);
        }
    }
    // --- T13 defer-rescale online softmax (exp2 domain, native v_exp_f32)
    float mx = S[0][0];
#pragma unroll
    for (int j = 0; j < 4; ++j)
#pragma unroll
      for (int r = 0; r < 4; ++r) mx = fmaxf(mx, S[j][r]);
    if (__ballot(mx > mrow + 11.5f)) {
      // rare path (tile 0 + genuine max growth): full reduce + rescale
      float fm = fmaxf(mx, __shfl_xor(mx, 16, 64));
      fm = fmaxf(fm, __shfl_xor(fm, 32, 64));
      float nm = fmaxf(mrow, fm);
      float alpha = exp2n(mrow - nm);
      float av[4];
#pragma unroll
      for (int r = 0; r < 4; ++r) av[r] = __shfl(alpha, quad * 4 + r, 64);
#pragma unroll
      for (int jj = 0; jj < 4; ++jj)
#pragma unroll
        for (int r = 0; r < 4; ++r) o[jj][r] *= av[r];
      lpart *= alpha;
      mrow = nm;
    }
    float rs = 0.f;
#pragma unroll
    for (int j = 0; j < 4; ++j)
#pragma unroll
      for (int r = 0; r < 4; ++r) {
        float p = exp2n(S[j][r] - mrow);  // bounded by 2^11.5
        S[j][r] = p;
        rs += p;
      }
    lpart += rs;  // per-lane partial (this quad's kv slice); reduced at end
    __syncthreads();  // B: K frags consumed; Ks reusable as P
#pragma unroll
    for (int j = 0; j < 4; ++j) {
      alignas(8) bf16 tmp[4];
#pragma unroll
      for (int r = 0; r < 4; ++r) tmp[r] = __float2bfloat16(S[j][r]);
      *(uint64_t*)(rowP + j * 16 + quad * 4) = *(const uint64_t*)tmp;
    }
    __threadfence_block();
    __builtin_amdgcn_wave_barrier();
    bf16x8 pf0 = *(const bf16x8*)(rowP + quad * 8);
    bf16x8 pf1 = *(const bf16x8*)(rowP + 32 + quad * 8);
    __builtin_amdgcn_s_setprio(1);
#pragma unroll
    for (int jj = 0; jj < 4; ++jj) {
      bf16x8 vf0 = read_frag_swz(Vs, jj * 16 + c, quad);
      bf16x8 vf1 = read_frag_swz(Vs, jj * 16 + c, quad + 4);
      o[jj] = mfma16(pf0, vf0, o[jj]);
      o[jj] = mfma16(pf1, vf1, o[jj]);
    }
    __builtin_amdgcn_s_setprio(0);
    __syncthreads();  // C: P/V consumed; safe to restage
  }

  // one-time l reduction: per-lane quad partials -> row totals.
  // ONE divide per lane (on lsum), then broadcast the reciprocal --
  // replaces 16 per-output divides (each ~10 VALU ops on gfx950).
  float lsum = lpart + __shfl_xor(lpart, 16, 64);
  lsum += __shfl_xor(lsum, 32, 64);
  float linv = 1.0f / lsum;
  float li4[4];
#pragma unroll
  for (int r = 0; r < 4; ++r) li4[r] = __shfl(linv, quad * 4 + r, 64);
#pragma unroll
  for (int jj = 0; jj < 4; ++jj)
#pragma unroll
    for (int r = 0; r < 4; ++r) {
      int qi = qb + quad * 4 + r;
      out[(((size_t)b * 1024 + qi) * 16 + h) * 64 + jj * 16 + c] =
          __float2bfloat16(o[jj][r] * li4[r]);
    }
}

// ---------------------------------------------------------------------------
// Memory plan:
//   d_out (32 MB fp32): [0,16M) q bf16 | [16M,32M) x_bf16.
//   ws: k 4MB @0 | vT 4MB @4M | attn 16MB @8M
//   Wq/Wk/Wv_bf @8M/10M/10.5M (attn region, dead before attn_kernel writes).
//   Wo_bf: ws+24M when ws_size >= 26MB (untouched during attn -> converted
//   EARLY inside cvt_all, removing the serial cvt between attn and gemm_o);
//   else fallback to ws@0 converted after attn (r9 scheme, byte-identical).
// ---------------------------------------------------------------------------
extern "C" void kernel_launch(void* const* d_in, const int* in_sizes, int n_in,
                              void* d_out, int out_size, void* d_ws,
                              size_t ws_size, hipStream_t stream) {
  const float* x = (const float*)d_in[0];
  const float* Wq = (const float*)d_in[1];
  const float* Wk = (const float*)d_in[2];
  const float* Wv = (const float*)d_in[3];
  const float* Wo = (const float*)d_in[4];
  const float* E = (const float*)d_in[5];

  char* ws = (char*)d_ws;
  bf16* q_ws = (bf16*)d_out;                           // [0,16M) of d_out
  bf16* x_bf = (bf16*)((char*)d_out + (16ull << 20));  // [16M,32M) of d_out
  bf16* k_ws = (bf16*)(ws);
  bf16* vT = (bf16*)(ws + (4ull << 20));
  bf16* attn = (bf16*)(ws + (8ull << 20));
  bf16* Wq_bf = (bf16*)(ws + (8ull << 20));            // 2 MB   (attn region)
  bf16* Wk_bf = (bf16*)(ws + (10ull << 20));           // 0.5 MB (attn region)
  bf16* Wv_bf = (bf16*)(ws + (10ull << 20) + (512ull << 10));  // 0.5 MB
  float* outp = (float*)d_out;

  // ws_size is launch-invariant -> stable branch, graph-capture safe.
  const bool early_wo = ws_size >= (26ull << 20);
  bf16* Wo_bf = early_wo ? (bf16*)(ws + (24ull << 20)) : (bf16*)ws;

  cvt_all<<<early_wo ? 4608 : 3584, 256, 0, stream>>>(
      x, Wq, Wk, Wv, Wo, x_bf, Wq_bf, Wk_bf, Wv_bf, Wo_bf);
  gemm_qkv<<<dim3(12, 64), 256, 0, stream>>>(x_bf, Wq_bf, Wk_bf, Wv_bf,
                                             q_ws, k_ws, vT);
  attn_kernel<<<dim3(16, 128), 256, 0, stream>>>(q_ws, k_ws, vT, E, attn);
  if (!early_wo) cvt_bf16<<<1024, 256, 0, stream>>>(Wo, Wo_bf, 262144);
  gemm_o<<<dim3(8, 64), 256, 0, stream>>>(attn, Wo_bf, outp);
}